// Round 6
// baseline (497.661 us; speedup 1.0000x reference)
//
#include <hip/hip_runtime.h>

// ---- problem constants ----
#define T_TOK   2048
#define HID     2048
#define NHEADS  32
#define NKV     4
#define HD      128
#define QSZ     4096          // 32*128
#define KVSZ    512           // 4*128
#define QKVW    5120          // QSZ + 2*KVSZ

typedef unsigned short u16;
typedef __bf16 bf16x8 __attribute__((ext_vector_type(8)));
typedef float  f32x4  __attribute__((ext_vector_type(4)));

__device__ __forceinline__ u16 f2bf(float f) {
  unsigned int u = __float_as_uint(f);
  u += 0x7fffu + ((u >> 16) & 1u);   // RNE
  return (u16)(u >> 16);
}

// async 16B global -> LDS (wave-uniform base + lane*16 semantics)
__device__ __forceinline__ void gl2lds16(const void* g, void* l) {
  __builtin_amdgcn_global_load_lds(
      (const __attribute__((address_space(1))) unsigned int*)g,
      (__attribute__((address_space(3))) unsigned int*)l, 16, 0, 0);
}

// ---------------- fused fp32 -> bf16 convert (3 arrays, one launch) ---------
__global__ void cvt3_f32_bf16(const float* __restrict__ in0, u16* __restrict__ o0, int n0,
                              const float* __restrict__ in1, u16* __restrict__ o1, int n1,
                              const float* __restrict__ in2, u16* __restrict__ o2, int n2) {
  int i = blockIdx.x * blockDim.x + threadIdx.x;
  const float* in; u16* out;
  if (i < n0)            { in = in0; out = o0; }
  else if (i < n0 + n1)  { in = in1; out = o1; i -= n0; }
  else if (i < n0+n1+n2) { in = in2; out = o2; i -= n0 + n1; }
  else return;
  float4 v = ((const float4*)in)[i];
  ushort4 o;
  o.x = f2bf(v.x); o.y = f2bf(v.y); o.z = f2bf(v.z); o.w = f2bf(v.w);
  ((ushort4*)out)[i] = o;
}

// ---------------- NT GEMM: C[m][n] = sum_k A[m][k]*B[n][k] ----------------
template<int BM>
__launch_bounds__(256, 2)
__global__ void gemm_nt(const u16* __restrict__ A, const u16* __restrict__ B,
                        float* __restrict__ C, int M, int N, int K) {
  constexpr int MI = BM / 32;          // m-tiles per wave
  __shared__ __align__(16) u16 As[BM * 32];
  __shared__ __align__(16) u16 Bs[128 * 32];
  const int tid  = threadIdx.x;
  const int wave = tid >> 6, lane = tid & 63;
  const int l15  = lane & 15, quad = lane >> 4;
  const int wr   = wave >> 1, wc = wave & 1;

  const u16* Ab = A + (size_t)blockIdx.y * BM * K;
  const u16* Bb = B + (size_t)blockIdx.x * 128 * K;

  f32x4 acc[MI][4];
#pragma unroll
  for (int i = 0; i < MI; i++)
#pragma unroll
    for (int j = 0; j < 4; j++) acc[i][j] = (f32x4){0.f, 0.f, 0.f, 0.f};

  constexpr int ACH = BM * 32 / 8;     // 16B chunks in A tile
  for (int k0 = 0; k0 < K; k0 += 32) {
#pragma unroll
    for (int s = 0; s < (ACH + 512) / 256; s++) {
      int c = tid + s * 256;
      if (c < ACH) {
        int row = c >> 2, co = (c & 3) * 8;
        gl2lds16(Ab + (size_t)row * K + k0 + co, &As[c * 8]);
      } else {
        int c2 = c - ACH;
        int row = c2 >> 2, co = (c2 & 3) * 8;
        gl2lds16(Bb + (size_t)row * K + k0 + co, &Bs[c2 * 8]);
      }
    }
    __syncthreads();
    bf16x8 af[MI], bf[4];
#pragma unroll
    for (int i = 0; i < MI; i++) af[i] = *(const bf16x8*)&As[(wr * (BM / 2) + i * 16 + l15) * 32 + quad * 8];
#pragma unroll
    for (int j = 0; j < 4; j++) bf[j] = *(const bf16x8*)&Bs[(wc * 64 + j * 16 + l15) * 32 + quad * 8];
#pragma unroll
    for (int i = 0; i < MI; i++)
#pragma unroll
      for (int j = 0; j < 4; j++)
        acc[i][j] = __builtin_amdgcn_mfma_f32_16x16x32_bf16(af[i], bf[j], acc[i][j], 0, 0, 0);
    __syncthreads();
  }

  float* Cb = C + (size_t)blockIdx.y * BM * N + (size_t)blockIdx.x * 128;
#pragma unroll
  for (int i = 0; i < MI; i++) {
    int rbase = wr * (BM / 2) + i * 16 + quad * 4;
#pragma unroll
    for (int j = 0; j < 4; j++) {
      int col = wc * 64 + j * 16 + l15;
#pragma unroll
      for (int r = 0; r < 4; r++) Cb[(size_t)(rbase + r) * N + col] = acc[i][j][r];
    }
  }
}

// ---------------- RMSNorm + RoPE + cast (one block per token) ----------------
__global__ void norm_rope(const float* __restrict__ qkv, const int* __restrict__ pos,
                          const float* __restrict__ qw, const float* __restrict__ kw,
                          u16* __restrict__ qB, u16* __restrict__ kB, u16* __restrict__ vB) {
  const int t = blockIdx.x;
  const int wave = threadIdx.x >> 6, l = threadIdx.x & 63;
  const float* row = qkv + (size_t)t * QKVW;

  const float p = (float)pos[t];
  const float fr = p * exp2f(-(float)l * 0.20762050593046014f);
  float sn, cs;
  sincosf(fr, &sn, &cs);

  for (int slot = wave; slot < 40; slot += 4) {
    if (slot < 36) {
      const int   base = (slot < 32) ? slot * 128 : 4096 + (slot - 32) * 128;
      const float* w   = (slot < 32) ? qw : kw;
      float x1 = row[base + l], x2 = row[base + 64 + l];
      float ss = x1 * x1 + x2 * x2;
#pragma unroll
      for (int off = 32; off; off >>= 1) ss += __shfl_xor(ss, off);
      float rs = rsqrtf(ss * (1.f / 128.f) + 1e-6f);
      float n1 = x1 * rs * w[l], n2 = x2 * rs * w[64 + l];
      float o1 = n1 * cs - n2 * sn;
      float o2 = n2 * cs + n1 * sn;
      if (slot < 32) {
        o1 *= 0.08838834764831845f;   // fold 1/sqrt(HD) into q
        o2 *= 0.08838834764831845f;
        qB[(size_t)t * QSZ + slot * 128 + l]      = f2bf(o1);
        qB[(size_t)t * QSZ + slot * 128 + 64 + l] = f2bf(o2);
      } else {
        kB[(size_t)t * KVSZ + (slot - 32) * 128 + l]      = f2bf(o1);
        kB[(size_t)t * KVSZ + (slot - 32) * 128 + 64 + l] = f2bf(o2);
      }
    } else {
      int vh = slot - 36;
      float x1 = row[4608 + vh * 128 + l];
      float x2 = row[4608 + vh * 128 + 64 + l];
      vB[(size_t)t * KVSZ + vh * 128 + l]      = f2bf(x1);
      vB[(size_t)t * KVSZ + vh * 128 + 64 + l] = f2bf(x2);
    }
  }
}

// ---------------- V transpose: vB[t][kvh*128+d] -> vT[kvh*128+d][t] ---------
__global__ void transpose_v(const u16* __restrict__ vB, u16* __restrict__ vT) {
  const int vh = blockIdx.y, tb = blockIdx.x;
  const int d0 = threadIdx.x >> 4;          // + s*16
  const int tc = (threadIdx.x & 15) * 8;
#pragma unroll
  for (int s = 0; s < 8; s++) {
    int dd = d0 + s * 16;
    uint4 v; u16* pv = (u16*)&v;
#pragma unroll
    for (int j = 0; j < 8; j++)
      pv[j] = vB[(size_t)(tb * 128 + tc + j) * KVSZ + vh * 128 + dd];
    *(uint4*)&vT[((size_t)vh * 128 + dd) * T_TOK + tb * 128 + tc] = v;
  }
}

// ---------------- flash attention (causal, GQA 8:1) -------------------------
// 64-key tiles, double-buffered K/V LDS, per-wave-strip P buffer, ONE barrier
// per tile. launch_bounds(256,1): the (256,2) variant capped VGPRs at 128 and
// spilled ~70 regs to scratch every iteration (r5: WRITE_SIZE 93MB vs 17MB
// output). Demand ~195 regs <= 256 keeps 2 waves/SIMD = LDS-limited occupancy.
__launch_bounds__(256, 1)
__global__ void attn_fa(const u16* __restrict__ qB, const u16* __restrict__ kB,
                        const u16* __restrict__ vT, u16* __restrict__ oB) {
  const int qb  = (blockIdx.y < 16) ? (15 - (int)blockIdx.x) : (int)blockIdx.x;
  const int h   = blockIdx.y;
  const int kvh = h >> 3;
  __shared__ __align__(16) u16 Kb[2][64 * 16 * 8];   // [key][d], swizzled, 16 KB each
  __shared__ __align__(16) u16 Vb[2][128 * 8 * 8];   // [d][key], swizzled, 16 KB each
  __shared__ __align__(16) u16 Pb[128 * 8 * 8];      // [row][key], swizzled, 16 KB

  const int tid  = threadIdx.x;
  const int wave = tid >> 6, lane = tid & 63;
  const int l15  = lane & 15, quad = lane >> 4;

  // staging geometry
  const int krow = tid >> 4, kmc = tid & 15;   // K: rows krow+s*16, chunk kmc (of 16)
  const int vrow = tid >> 3, vmc = tid & 7;    // V: rows vrow+s*32, chunk vmc (of 8)

  bf16x8 qf[2][4];
#pragma unroll
  for (int mi = 0; mi < 2; mi++)
#pragma unroll
    for (int ds = 0; ds < 4; ds++)
      qf[mi][ds] = *(const bf16x8*)(qB + (size_t)(qb * 128 + wave * 32 + mi * 16 + l15) * QSZ
                                       + h * 128 + ds * 32 + quad * 8);

  f32x4 o[2][8];
#pragma unroll
  for (int mi = 0; mi < 2; mi++)
#pragma unroll
    for (int ni = 0; ni < 8; ni++) o[mi][ni] = (f32x4){0.f, 0.f, 0.f, 0.f};
  float mrow[2][4], lrow[2][4];
#pragma unroll
  for (int mi = 0; mi < 2; mi++)
#pragma unroll
    for (int r = 0; r < 4; r++) { mrow[mi][r] = -3.0e38f; lrow[mi][r] = 0.f; }

  const int nt = 2 * qb + 2;                   // 64-key tiles to process

  uint4 kreg[4], vreg[4];
#pragma unroll
  for (int s = 0; s < 4; s++) {                // preload tile 0
    kreg[s] = *(const uint4*)(kB + (size_t)(krow + s * 16) * KVSZ + kvh * 128 + kmc * 8);
    vreg[s] = *(const uint4*)(vT + ((size_t)kvh * 128 + vrow + s * 32) * T_TOK + vmc * 8);
  }

  for (int kt = 0; kt < nt; kt++) {
    const int cur = kt & 1;
    // 1) staged regs -> swizzled LDS[cur] (waits on loads issued last tile)
#pragma unroll
    for (int s = 0; s < 4; s++) {
      int r  = krow + s * 16;
      *(uint4*)&Kb[cur][(r * 16 + (kmc ^ (r & 15))) * 8] = kreg[s];
      int rv = vrow + s * 32;
      *(uint4*)&Vb[cur][(rv * 8 + (vmc ^ (rv & 7))) * 8] = vreg[s];
    }
    // 2) single barrier (nothing outstanding -> no vmcnt drain stall)
    __syncthreads();
    // 3) issue next tile's loads (consumed at next iter's step 1)
    const int kn = (kt + 1 < nt) ? kt + 1 : kt;
#pragma unroll
    for (int s = 0; s < 4; s++) {
      kreg[s] = *(const uint4*)(kB + (size_t)(kn * 64 + krow + s * 16) * KVSZ + kvh * 128 + kmc * 8);
      vreg[s] = *(const uint4*)(vT + ((size_t)kvh * 128 + vrow + s * 32) * T_TOK + kn * 64 + vmc * 8);
    }

    // 4) S = Q K^T (32 rows x 64 keys per wave)
    f32x4 sc[2][4];
#pragma unroll
    for (int mi = 0; mi < 2; mi++)
#pragma unroll
      for (int ni = 0; ni < 4; ni++) sc[mi][ni] = (f32x4){0.f, 0.f, 0.f, 0.f};
#pragma unroll
    for (int ds = 0; ds < 4; ds++) {
#pragma unroll
      for (int ni = 0; ni < 4; ni++) {
        bf16x8 kf = *(const bf16x8*)&Kb[cur][((ni * 16 + l15) * 16 + ((ds * 4 + quad) ^ l15)) * 8];
        sc[0][ni] = __builtin_amdgcn_mfma_f32_16x16x32_bf16(qf[0][ds], kf, sc[0][ni], 0, 0, 0);
        sc[1][ni] = __builtin_amdgcn_mfma_f32_16x16x32_bf16(qf[1][ds], kf, sc[1][ni], 0, 0, 0);
      }
    }

    if (kt >= 2 * qb) {  // tiles intersecting the diagonal
#pragma unroll
      for (int mi = 0; mi < 2; mi++)
#pragma unroll
        for (int ni = 0; ni < 4; ni++)
#pragma unroll
          for (int r = 0; r < 4; r++) {
            int key = kt * 64 + ni * 16 + l15;
            int rw  = qb * 128 + wave * 32 + mi * 16 + quad * 4 + r;
            if (key > rw) sc[mi][ni][r] = -1.0e30f;
          }
    }

    // online softmax (stats per 16-lane row-group)
#pragma unroll
    for (int mi = 0; mi < 2; mi++)
#pragma unroll
      for (int r = 0; r < 4; r++) {
        float mx = sc[mi][0][r];
#pragma unroll
        for (int ni = 1; ni < 4; ni++) mx = fmaxf(mx, sc[mi][ni][r]);
#pragma unroll
        for (int off = 1; off < 16; off <<= 1) mx = fmaxf(mx, __shfl_xor(mx, off));
        float mn = fmaxf(mrow[mi][r], mx);
        float al = __expf(mrow[mi][r] - mn);
        mrow[mi][r] = mn;
        float rs = 0.f;
#pragma unroll
        for (int ni = 0; ni < 4; ni++) {
          float pv = __expf(sc[mi][ni][r] - mn);
          sc[mi][ni][r] = pv;
          rs += pv;
        }
#pragma unroll
        for (int off = 1; off < 16; off <<= 1) rs += __shfl_xor(rs, off);
        lrow[mi][r] = lrow[mi][r] * al + rs;
#pragma unroll
        for (int ni = 0; ni < 8; ni++) o[mi][ni][r] *= al;
      }

    // P (own 32-row strip) -> swizzled Pb; no barrier needed (strip-private)
#pragma unroll
    for (int mi = 0; mi < 2; mi++)
#pragma unroll
      for (int ni = 0; ni < 4; ni++)
#pragma unroll
        for (int r = 0; r < 4; r++) {
          int row = wave * 32 + mi * 16 + quad * 4 + r;
          Pb[(row * 8 + ((ni * 2 + (l15 >> 3)) ^ (row & 7))) * 8 + (l15 & 7)] =
              f2bf(sc[mi][ni][r]);
        }

    // O += P V  (A = own P strip, B = V^T tile)
#pragma unroll
    for (int ks = 0; ks < 2; ks++) {
      bf16x8 pf0 = *(const bf16x8*)&Pb[((wave * 32 + l15) * 8 + ((ks * 4 + quad) ^ (l15 & 7))) * 8];
      bf16x8 pf1 = *(const bf16x8*)&Pb[((wave * 32 + 16 + l15) * 8 + ((ks * 4 + quad) ^ (l15 & 7))) * 8];
#pragma unroll
      for (int ni = 0; ni < 8; ni++) {
        bf16x8 vf = *(const bf16x8*)&Vb[cur][((ni * 16 + l15) * 8 + ((ks * 4 + quad) ^ (l15 & 7))) * 8];
        o[0][ni] = __builtin_amdgcn_mfma_f32_16x16x32_bf16(pf0, vf, o[0][ni], 0, 0, 0);
        o[1][ni] = __builtin_amdgcn_mfma_f32_16x16x32_bf16(pf1, vf, o[1][ni], 0, 0, 0);
      }
    }
  }

  // epilogue: O / l -> bf16
#pragma unroll
  for (int mi = 0; mi < 2; mi++)
#pragma unroll
    for (int ni = 0; ni < 8; ni++)
#pragma unroll
      for (int r = 0; r < 4; r++) {
        int t = qb * 128 + wave * 32 + mi * 16 + quad * 4 + r;
        float val = o[mi][ni][r] / lrow[mi][r];
        oB[(size_t)t * QSZ + h * 128 + ni * 16 + l15] = f2bf(val);
      }
}

// ---------------- launch ----------------
extern "C" void kernel_launch(void* const* d_in, const int* in_sizes, int n_in,
                              void* d_out, int out_size, void* d_ws, size_t ws_size,
                              hipStream_t stream) {
  const int*   positions = (const int*)d_in[0];
  const float* hidden    = (const float*)d_in[1];
  const float* w_qkv     = (const float*)d_in[2];
  const float* w_o       = (const float*)d_in[3];
  const float* qw        = (const float*)d_in[4];
  const float* kw        = (const float*)d_in[5];
  float* out = (float*)d_out;
  char*  ws  = (char*)d_ws;

  u16* hiddenB = (u16*)ws;
  u16* wqkvB   = hiddenB + (size_t)HID * HID;
  u16* woB     = wqkvB + (size_t)QKVW * HID;                 // separate (cvt fused up front)
  size_t off1  = ((size_t)HID * HID + (size_t)QKVW * HID + (size_t)HID * QSZ) * 2;
  float* qkvF  = (float*)(ws + off1);
  u16*   attnB = (u16*)(ws + off1);                          // alias (dead qkvF)
  size_t off2  = off1 + (size_t)T_TOK * QKVW * 4;
  u16* qBuf = (u16*)(ws + off2);
  size_t off3  = off2 + (size_t)T_TOK * QSZ * 2;
  u16* kBuf = (u16*)(ws + off3);
  size_t off4  = off3 + (size_t)T_TOK * KVSZ * 2;
  u16* vTb  = (u16*)(ws + off4);
  size_t off5  = off4 + (size_t)T_TOK * KVSZ * 2;
  u16* vBuf = (u16*)(ws + off5);

  const int n0 = HID * HID / 4, n1 = QKVW * HID / 4, n2 = HID * QSZ / 4;
  cvt3_f32_bf16<<<(n0 + n1 + n2 + 255) / 256, 256, 0, stream>>>(
      hidden, hiddenB, n0, w_qkv, wqkvB, n1, w_o, woB, n2);

  gemm_nt<128><<<dim3(QKVW / 128, T_TOK / 128), 256, 0, stream>>>(hiddenB, wqkvB, qkvF, T_TOK, QKVW, HID);

  norm_rope<<<T_TOK, 256, 0, stream>>>(qkvF, positions, qw, kw, qBuf, kBuf, vBuf);

  transpose_v<<<dim3(T_TOK / 128, NKV), 256, 0, stream>>>(vBuf, vTb);

  attn_fa<<<dim3(T_TOK / 128, NHEADS), 256, 0, stream>>>(qBuf, kBuf, vTb, attnB);

  gemm_nt<64><<<dim3(HID / 128, T_TOK / 64), 256, 0, stream>>>(attnB, woB, out, T_TOK, HID, QSZ);
}

// Round 7
// 424.448 us; speedup vs baseline: 1.1725x; 1.1725x over previous
//
#include <hip/hip_runtime.h>

// ---- problem constants ----
#define T_TOK   2048
#define HID     2048
#define NHEADS  32
#define NKV     4
#define HD      128
#define QSZ     4096          // 32*128
#define KVSZ    512           // 4*128
#define QKVW    5120          // QSZ + 2*KVSZ

typedef unsigned short u16;
typedef __bf16 bf16x8 __attribute__((ext_vector_type(8)));
typedef float  f32x4  __attribute__((ext_vector_type(4)));

__device__ __forceinline__ u16 f2bf(float f) {
  unsigned int u = __float_as_uint(f);
  u += 0x7fffu + ((u >> 16) & 1u);   // RNE
  return (u16)(u >> 16);
}

// async 16B global -> LDS (wave-uniform base + lane*16 semantics)
__device__ __forceinline__ void gl2lds16(const void* g, void* l) {
  __builtin_amdgcn_global_load_lds(
      (const __attribute__((address_space(1))) unsigned int*)g,
      (__attribute__((address_space(3))) unsigned int*)l, 16, 0, 0);
}

// ---------------- fused fp32 -> bf16 convert (3 arrays, one launch) ---------
__global__ void cvt3_f32_bf16(const float* __restrict__ in0, u16* __restrict__ o0, int n0,
                              const float* __restrict__ in1, u16* __restrict__ o1, int n1,
                              const float* __restrict__ in2, u16* __restrict__ o2, int n2) {
  int i = blockIdx.x * blockDim.x + threadIdx.x;
  const float* in; u16* out;
  if (i < n0)            { in = in0; out = o0; }
  else if (i < n0 + n1)  { in = in1; out = o1; i -= n0; }
  else if (i < n0+n1+n2) { in = in2; out = o2; i -= n0 + n1; }
  else return;
  float4 v = ((const float4*)in)[i];
  ushort4 o;
  o.x = f2bf(v.x); o.y = f2bf(v.y); o.z = f2bf(v.z); o.w = f2bf(v.w);
  ((ushort4*)out)[i] = o;
}

// ---------------- NT GEMM: C[m][n] = sum_k A[m][k]*B[n][k] ----------------
template<int BM>
__launch_bounds__(256, 2)
__global__ void gemm_nt(const u16* __restrict__ A, const u16* __restrict__ B,
                        float* __restrict__ C, int M, int N, int K) {
  constexpr int MI = BM / 32;          // m-tiles per wave
  __shared__ __align__(16) u16 As[BM * 32];
  __shared__ __align__(16) u16 Bs[128 * 32];
  const int tid  = threadIdx.x;
  const int wave = tid >> 6, lane = tid & 63;
  const int l15  = lane & 15, quad = lane >> 4;
  const int wr   = wave >> 1, wc = wave & 1;

  const u16* Ab = A + (size_t)blockIdx.y * BM * K;
  const u16* Bb = B + (size_t)blockIdx.x * 128 * K;

  f32x4 acc[MI][4];
#pragma unroll
  for (int i = 0; i < MI; i++)
#pragma unroll
    for (int j = 0; j < 4; j++) acc[i][j] = (f32x4){0.f, 0.f, 0.f, 0.f};

  constexpr int ACH = BM * 32 / 8;     // 16B chunks in A tile
  for (int k0 = 0; k0 < K; k0 += 32) {
#pragma unroll
    for (int s = 0; s < (ACH + 512) / 256; s++) {
      int c = tid + s * 256;
      if (c < ACH) {
        int row = c >> 2, co = (c & 3) * 8;
        gl2lds16(Ab + (size_t)row * K + k0 + co, &As[c * 8]);
      } else {
        int c2 = c - ACH;
        int row = c2 >> 2, co = (c2 & 3) * 8;
        gl2lds16(Bb + (size_t)row * K + k0 + co, &Bs[c2 * 8]);
      }
    }
    __syncthreads();
    bf16x8 af[MI], bf[4];
#pragma unroll
    for (int i = 0; i < MI; i++) af[i] = *(const bf16x8*)&As[(wr * (BM / 2) + i * 16 + l15) * 32 + quad * 8];
#pragma unroll
    for (int j = 0; j < 4; j++) bf[j] = *(const bf16x8*)&Bs[(wc * 64 + j * 16 + l15) * 32 + quad * 8];
#pragma unroll
    for (int i = 0; i < MI; i++)
#pragma unroll
      for (int j = 0; j < 4; j++)
        acc[i][j] = __builtin_amdgcn_mfma_f32_16x16x32_bf16(af[i], bf[j], acc[i][j], 0, 0, 0);
    __syncthreads();
  }

  float* Cb = C + (size_t)blockIdx.y * BM * N + (size_t)blockIdx.x * 128;
#pragma unroll
  for (int i = 0; i < MI; i++) {
    int rbase = wr * (BM / 2) + i * 16 + quad * 4;
#pragma unroll
    for (int j = 0; j < 4; j++) {
      int col = wc * 64 + j * 16 + l15;
#pragma unroll
      for (int r = 0; r < 4; r++) Cb[(size_t)(rbase + r) * N + col] = acc[i][j][r];
    }
  }
}

// ---------------- RMSNorm + RoPE + cast (one block per token) ----------------
__global__ void norm_rope(const float* __restrict__ qkv, const int* __restrict__ pos,
                          const float* __restrict__ qw, const float* __restrict__ kw,
                          u16* __restrict__ qB, u16* __restrict__ kB, u16* __restrict__ vB) {
  const int t = blockIdx.x;
  const int wave = threadIdx.x >> 6, l = threadIdx.x & 63;
  const float* row = qkv + (size_t)t * QKVW;

  const float p = (float)pos[t];
  const float fr = p * exp2f(-(float)l * 0.20762050593046014f);
  float sn, cs;
  sincosf(fr, &sn, &cs);

  for (int slot = wave; slot < 40; slot += 4) {
    if (slot < 36) {
      const int   base = (slot < 32) ? slot * 128 : 4096 + (slot - 32) * 128;
      const float* w   = (slot < 32) ? qw : kw;
      float x1 = row[base + l], x2 = row[base + 64 + l];
      float ss = x1 * x1 + x2 * x2;
#pragma unroll
      for (int off = 32; off; off >>= 1) ss += __shfl_xor(ss, off);
      float rs = rsqrtf(ss * (1.f / 128.f) + 1e-6f);
      float n1 = x1 * rs * w[l], n2 = x2 * rs * w[64 + l];
      float o1 = n1 * cs - n2 * sn;
      float o2 = n2 * cs + n1 * sn;
      if (slot < 32) {
        o1 *= 0.08838834764831845f;   // fold 1/sqrt(HD) into q
        o2 *= 0.08838834764831845f;
        qB[(size_t)t * QSZ + slot * 128 + l]      = f2bf(o1);
        qB[(size_t)t * QSZ + slot * 128 + 64 + l] = f2bf(o2);
      } else {
        kB[(size_t)t * KVSZ + (slot - 32) * 128 + l]      = f2bf(o1);
        kB[(size_t)t * KVSZ + (slot - 32) * 128 + 64 + l] = f2bf(o2);
      }
    } else {
      int vh = slot - 36;
      float x1 = row[4608 + vh * 128 + l];
      float x2 = row[4608 + vh * 128 + 64 + l];
      vB[(size_t)t * KVSZ + vh * 128 + l]      = f2bf(x1);
      vB[(size_t)t * KVSZ + vh * 128 + 64 + l] = f2bf(x2);
    }
  }
}

// ---------------- V transpose: vB[t][kvh*128+d] -> vT[kvh*128+d][t] ---------
__global__ void transpose_v(const u16* __restrict__ vB, u16* __restrict__ vT) {
  const int vh = blockIdx.y, tb = blockIdx.x;
  const int d0 = threadIdx.x >> 4;          // + s*16
  const int tc = (threadIdx.x & 15) * 8;
#pragma unroll
  for (int s = 0; s < 8; s++) {
    int dd = d0 + s * 16;
    uint4 v; u16* pv = (u16*)&v;
#pragma unroll
    for (int j = 0; j < 8; j++)
      pv[j] = vB[(size_t)(tb * 128 + tc + j) * KVSZ + vh * 128 + dd];
    *(uint4*)&vT[((size_t)vh * 128 + dd) * T_TOK + tb * 128 + tc] = v;
  }
}

// ---------------- flash attention (causal, GQA 8:1) -------------------------
// 512 threads / 8 waves, each wave owns a 16-row q-strip: per-wave register
// demand ~110 <= 128 cap, so launch_bounds(512,4) gives NO spill (r5 horn) AND
// 16 waves/CU (2x r6's 8, the other horn). 64-key tiles, double-buffered K/V,
// XOR-swizzled LDS (0 conflicts, r5/r6-verified formulas), ONE barrier/tile.
__launch_bounds__(512, 4)
__global__ void attn_fa(const u16* __restrict__ qB, const u16* __restrict__ kB,
                        const u16* __restrict__ vT, u16* __restrict__ oB) {
  const int qb  = (blockIdx.y < 16) ? (15 - (int)blockIdx.x) : (int)blockIdx.x;
  const int h   = blockIdx.y;
  const int kvh = h >> 3;
  __shared__ __align__(16) u16 Kb[2][64 * 16 * 8];   // [key][d], swizzled, 16 KB each
  __shared__ __align__(16) u16 Vb[2][128 * 8 * 8];   // [d][key], swizzled, 16 KB each
  __shared__ __align__(16) u16 Pb[128 * 8 * 8];      // [row][key], swizzled, 16 KB

  const int tid  = threadIdx.x;
  const int wave = tid >> 6, lane = tid & 63;
  const int l15  = lane & 15, quad = lane >> 4;

  // staging geometry (512 threads): K rows krow+s*32, V rows vrow+s*64
  const int krow = tid >> 4, kmc = tid & 15;
  const int vrow = tid >> 3, vmc = tid & 7;

  bf16x8 qf[4];
#pragma unroll
  for (int ds = 0; ds < 4; ds++)
    qf[ds] = *(const bf16x8*)(qB + (size_t)(qb * 128 + wave * 16 + l15) * QSZ
                                 + h * 128 + ds * 32 + quad * 8);

  f32x4 o[8];
#pragma unroll
  for (int ni = 0; ni < 8; ni++) o[ni] = (f32x4){0.f, 0.f, 0.f, 0.f};
  float mrow[4], lrow[4];
#pragma unroll
  for (int r = 0; r < 4; r++) { mrow[r] = -3.0e38f; lrow[r] = 0.f; }

  const int nt = 2 * qb + 2;                   // 64-key tiles

  uint4 kreg[2], vreg[2];
#pragma unroll
  for (int s = 0; s < 2; s++) {                // preload tile 0
    kreg[s] = *(const uint4*)(kB + (size_t)(krow + s * 32) * KVSZ + kvh * 128 + kmc * 8);
    vreg[s] = *(const uint4*)(vT + ((size_t)kvh * 128 + vrow + s * 64) * T_TOK + vmc * 8);
  }

  for (int kt = 0; kt < nt; kt++) {
    const int cur = kt & 1;
    // 1) staged regs -> swizzled LDS[cur] (vmcnt wait = loads from LAST tile)
#pragma unroll
    for (int s = 0; s < 2; s++) {
      int r  = krow + s * 32;
      *(uint4*)&Kb[cur][(r * 16 + (kmc ^ (r & 15))) * 8] = kreg[s];
      int rv = vrow + s * 64;
      *(uint4*)&Vb[cur][(rv * 8 + (vmc ^ (rv & 7))) * 8] = vreg[s];
    }
    // 2) single barrier
    __syncthreads();
    // 3) issue next tile's loads (consumed next iter step 1)
    const int kn = (kt + 1 < nt) ? kt + 1 : kt;
#pragma unroll
    for (int s = 0; s < 2; s++) {
      kreg[s] = *(const uint4*)(kB + (size_t)(kn * 64 + krow + s * 32) * KVSZ + kvh * 128 + kmc * 8);
      vreg[s] = *(const uint4*)(vT + ((size_t)kvh * 128 + vrow + s * 64) * T_TOK + kn * 64 + vmc * 8);
    }

    // 4) S = Q K^T (16 rows x 64 keys per wave)
    f32x4 sc[4];
#pragma unroll
    for (int ni = 0; ni < 4; ni++) sc[ni] = (f32x4){0.f, 0.f, 0.f, 0.f};
#pragma unroll
    for (int ds = 0; ds < 4; ds++) {
#pragma unroll
      for (int ni = 0; ni < 4; ni++) {
        bf16x8 kf = *(const bf16x8*)&Kb[cur][((ni * 16 + l15) * 16 + ((ds * 4 + quad) ^ l15)) * 8];
        sc[ni] = __builtin_amdgcn_mfma_f32_16x16x32_bf16(qf[ds], kf, sc[ni], 0, 0, 0);
      }
    }

    if (kt >= 2 * qb) {  // tiles intersecting the diagonal
#pragma unroll
      for (int ni = 0; ni < 4; ni++)
#pragma unroll
        for (int r = 0; r < 4; r++) {
          int key = kt * 64 + ni * 16 + l15;
          int rw  = qb * 128 + wave * 16 + quad * 4 + r;
          if (key > rw) sc[ni][r] = -1.0e30f;
        }
    }

    // online softmax (stats per 16-lane row-group)
#pragma unroll
    for (int r = 0; r < 4; r++) {
      float mx = sc[0][r];
#pragma unroll
      for (int ni = 1; ni < 4; ni++) mx = fmaxf(mx, sc[ni][r]);
#pragma unroll
      for (int off = 1; off < 16; off <<= 1) mx = fmaxf(mx, __shfl_xor(mx, off));
      float mn = fmaxf(mrow[r], mx);
      float al = __expf(mrow[r] - mn);
      mrow[r] = mn;
      float rs = 0.f;
#pragma unroll
      for (int ni = 0; ni < 4; ni++) {
        float pv = __expf(sc[ni][r] - mn);
        sc[ni][r] = pv;
        rs += pv;
      }
#pragma unroll
      for (int off = 1; off < 16; off <<= 1) rs += __shfl_xor(rs, off);
      lrow[r] = lrow[r] * al + rs;
#pragma unroll
      for (int ni = 0; ni < 8; ni++) o[ni][r] *= al;
    }

    // P (own 16-row strip) -> swizzled Pb; strip-private => no barrier
#pragma unroll
    for (int ni = 0; ni < 4; ni++)
#pragma unroll
      for (int r = 0; r < 4; r++) {
        int row = wave * 16 + quad * 4 + r;
        Pb[(row * 8 + ((ni * 2 + (l15 >> 3)) ^ (row & 7))) * 8 + (l15 & 7)] =
            f2bf(sc[ni][r]);
      }

    // O += P V  (A = own P strip, B = V^T tile)
#pragma unroll
    for (int ks = 0; ks < 2; ks++) {
      bf16x8 pf = *(const bf16x8*)&Pb[((wave * 16 + l15) * 8 + ((ks * 4 + quad) ^ (l15 & 7))) * 8];
#pragma unroll
      for (int ni = 0; ni < 8; ni++) {
        bf16x8 vf = *(const bf16x8*)&Vb[cur][((ni * 16 + l15) * 8 + ((ks * 4 + quad) ^ (l15 & 7))) * 8];
        o[ni] = __builtin_amdgcn_mfma_f32_16x16x32_bf16(pf, vf, o[ni], 0, 0, 0);
      }
    }
  }

  // epilogue: O / l -> bf16
#pragma unroll
  for (int ni = 0; ni < 8; ni++)
#pragma unroll
    for (int r = 0; r < 4; r++) {
      int t = qb * 128 + wave * 16 + quad * 4 + r;
      float val = o[ni][r] / lrow[r];
      oB[(size_t)t * QSZ + h * 128 + ni * 16 + l15] = f2bf(val);
    }
}

// ---------------- launch ----------------
extern "C" void kernel_launch(void* const* d_in, const int* in_sizes, int n_in,
                              void* d_out, int out_size, void* d_ws, size_t ws_size,
                              hipStream_t stream) {
  const int*   positions = (const int*)d_in[0];
  const float* hidden    = (const float*)d_in[1];
  const float* w_qkv     = (const float*)d_in[2];
  const float* w_o       = (const float*)d_in[3];
  const float* qw        = (const float*)d_in[4];
  const float* kw        = (const float*)d_in[5];
  float* out = (float*)d_out;
  char*  ws  = (char*)d_ws;

  u16* hiddenB = (u16*)ws;
  u16* wqkvB   = hiddenB + (size_t)HID * HID;
  u16* woB     = wqkvB + (size_t)QKVW * HID;
  size_t off1  = ((size_t)HID * HID + (size_t)QKVW * HID + (size_t)HID * QSZ) * 2;
  float* qkvF  = (float*)(ws + off1);
  u16*   attnB = (u16*)(ws + off1);                          // alias (dead qkvF)
  size_t off2  = off1 + (size_t)T_TOK * QKVW * 4;
  u16* qBuf = (u16*)(ws + off2);
  size_t off3  = off2 + (size_t)T_TOK * QSZ * 2;
  u16* kBuf = (u16*)(ws + off3);
  size_t off4  = off3 + (size_t)T_TOK * KVSZ * 2;
  u16* vTb  = (u16*)(ws + off4);
  size_t off5  = off4 + (size_t)T_TOK * KVSZ * 2;
  u16* vBuf = (u16*)(ws + off5);

  const int n0 = HID * HID / 4, n1 = QKVW * HID / 4, n2 = HID * QSZ / 4;
  cvt3_f32_bf16<<<(n0 + n1 + n2 + 255) / 256, 256, 0, stream>>>(
      hidden, hiddenB, n0, w_qkv, wqkvB, n1, w_o, woB, n2);

  gemm_nt<128><<<dim3(QKVW / 128, T_TOK / 128), 256, 0, stream>>>(hiddenB, wqkvB, qkvF, T_TOK, QKVW, HID);

  norm_rope<<<T_TOK, 256, 0, stream>>>(qkvF, positions, qw, kw, qBuf, kBuf, vBuf);

  transpose_v<<<dim3(T_TOK / 128, NKV), 256, 0, stream>>>(vBuf, vTb);

  attn_fa<<<dim3(T_TOK / 128, NHEADS), 512, 0, stream>>>(qBuf, kBuf, vTb, attnB);

  gemm_nt<64><<<dim3(HID / 128, T_TOK / 64), 256, 0, stream>>>(attnB, woB, out, T_TOK, HID, QSZ);
}